// Round 8
// baseline (134.036 us; speedup 1.0000x reference)
//
#include <hip/hip_runtime.h>

#define NN 2048
#define GG 64
#define CAP 64
#define TS 128
#define NT (NN / TS)                 // 16 tiles
#define NPAIR (NT * (NT + 1) / 2)    // 136 tile pairs
#define NTH 512

typedef unsigned long long u64;
typedef unsigned short u16;

__device__ __forceinline__ float iou4(float4 a, float4 b) {
    float w = fminf(a.z, b.z) - fmaxf(a.x, b.x) + 1.0f;
    float h = fminf(a.w, b.w) - fmaxf(a.y, b.y) + 1.0f;
    w = fmaxf(w, 0.0f);
    h = fmaxf(h, 0.0f);
    float ov = w * h;
    float aa = (a.z - a.x + 1.0f) * (a.w - a.y + 1.0f);
    float ab = (b.z - b.x + 1.0f) * (b.w - b.y + 1.0f);
    return ov / (aa + ab - ov);
}

__device__ __forceinline__ float wredf(float v) {
    for (int o = 32; o > 0; o >>= 1) v += __shfl_down(v, o);
    return v;
}
__device__ __forceinline__ int wredi(int v) {
    for (int o = 32; o > 0; o >>= 1) v += __shfl_down(v, o);
    return v;
}

// key: larger = earlier in selection order (higher score; tie -> lower original idx)
__device__ __forceinline__ u64 make_key(float sc, int j) {
    return ((u64)__float_as_uint(sc) << 32) | (u64)(NN - 1 - j);
}

__device__ __forceinline__ float4 load_box(const float* pb, int j) {
    return make_float4(pb[j * 5 + 0], pb[j * 5 + 1], pb[j * 5 + 2], pb[j * 5 + 3]);
}

struct PairSh {
    float4 Abox[TS], Bbox[TS];
    u64 Akey[TS], Bkey[TS];
    int Ag[TS], Bg[TS];
};
struct ScanSh {
    u64 keyL[NN];                       // 16 KB
    float sumA[NN];                     // 8 KB
    int cntA[NN];                       // 8 KB
    float4 gtb[GG];                     // 1 KB
    u64 firstk[GG];                     // 0.5 KB (max key among kept per gt; 0 = none)
    unsigned char st[NN];               // 0=unresolved 1=kept 2=killed
    unsigned char hk[NN];               // kept box suppressed someone
    unsigned char ccL[NN];              // capped list length
};
union Sh { PairSh p; ScanSh s; };       // pair data dead before scan init

__global__ __launch_bounds__(NTH) void fused_kernel(const int* __restrict__ gt_inds,
                                                    const float* __restrict__ gt_boxes,
                                                    const float* __restrict__ props,
                                                    int* __restrict__ colcnt, u16* __restrict__ colent,
                                                    int* __restrict__ ctrs, float* __restrict__ acc,
                                                    unsigned int* __restrict__ ctr2,
                                                    float* __restrict__ out, int B) {
    __shared__ Sh u;
    __shared__ u64 s_minkey;
    __shared__ int s_unres, s_pos, s_qcnt, s_pcnt;
    __shared__ float s_tpush, s_tpull;

    const int im = blockIdx.x / NPAIR;
    int p = blockIdx.x % NPAIR;
    const int tid = threadIdx.x;
    const int lane = tid & 63;
    const int base = im * NN;
    const float* pb = props + (size_t)im * NN * 5;
    const int* gbi = gt_inds + (size_t)im * NN;

    // ---- decode tile pair (a <= bt) ----
    int a = 0;
    {
        int q = p;
        while (q >= NT - a) { q -= NT - a; ++a; }
        p = blockIdx.x % NPAIR;           // keep p for the role test
        // bt below
    }
    int q2 = p;
    int aa = 0;
    while (q2 >= NT - aa) { q2 -= NT - aa; ++aa; }
    const int ta = aa, tb = aa + q2;

    // ---- stage tiles (boxes, keys, gt) from inputs ----
    if (tid < 2 * TS) {
        int half = tid >> 7;              // 0 = A, 1 = B
        int t = tid & (TS - 1);
        int j = (half ? tb : ta) * TS + t;
        float4 bx = load_box(pb, j);
        float sc = pb[j * 5 + 4];
        int g = gbi[j];
        if (half == 0) { u.p.Abox[t] = bx; u.p.Akey[t] = make_key(sc, j); u.p.Ag[t] = g; }
        else           { u.p.Bbox[t] = bx; u.p.Bkey[t] = make_key(sc, j); u.p.Bg[t] = g; }
    }
    __syncthreads();

    // ---- pair phase: record EARLIER (larger key) into LATER's CSR list ----
    {
        const int pr = tid & (TS - 1);    // row in tile A
        const int qh = tid >> 7;          // column quarter 0..3
        const float4 rb = u.p.Abox[pr];
        const u64 rk = u.p.Akey[pr];
        const int i = ta * TS + pr;
        if (u.p.Ag[pr] >= 0) {
            #pragma unroll 4
            for (int k = 0; k < TS / 4; ++k) {
                int jl = qh * (TS / 4) + k;
                if (ta == tb && jl <= pr) continue;   // each unordered pair once
                if (u.p.Bg[jl] < 0) continue;
                float v = iou4(rb, u.p.Bbox[jl]);
                if (v > 0.5f) {
                    int j = tb * TS + jl;
                    int late, early;
                    if (rk > u.p.Bkey[jl]) { late = j; early = i; }
                    else                   { late = i; early = j; }
                    int slot = atomicAdd(&colcnt[base + late], 1);
                    if (slot < CAP) colent[(size_t)(base + late) * CAP + slot] = (u16)early;
                }
            }
        }
    }
    __threadfence();                      // device-scope release of colcnt/colent
    __syncthreads();
    if (tid == 0) __hip_atomic_fetch_add(&ctrs[im], 1, __ATOMIC_RELEASE, __HIP_MEMORY_SCOPE_AGENT);
    if (p != 0) return;                   // only the per-image scan block continues

    // ---- scan-phase LDS init (independent of pair results; overlaps the wait) ----
    __syncthreads();                      // block's pair reads of u.p are done -> safe to overwrite
    if (tid == 0) { s_pos = 0; s_qcnt = 0; s_pcnt = 0; s_tpush = 0.f; s_tpull = 0.f; s_minkey = ~0ull; }
    if (tid < GG) {
        u.s.firstk[tid] = 0ull;
        const float* gt = gt_boxes + (size_t)im * GG * 4;
        u.s.gtb[tid] = make_float4(gt[tid * 4 + 0], gt[tid * 4 + 1], gt[tid * 4 + 2], gt[tid * 4 + 3]);
    }
    int lpos = 0;
    for (int j = tid; j < NN; j += NTH) {
        int g = gbi[j];
        u.s.st[j] = (g >= 0) ? 0 : 2;
        lpos += (g >= 0) ? 1 : 0;
        u.s.keyL[j] = make_key(pb[j * 5 + 4], j);
        u.s.cntA[j] = 0; u.s.sumA[j] = 0.f; u.s.hk[j] = 0;
    }
    lpos = wredi(lpos);
    if (lane == 0 && lpos) atomicAdd(&s_pos, lpos);

    // ---- wait for this image's pair blocks ----
    if (tid == 0) {
        while (__hip_atomic_load(&ctrs[im], __ATOMIC_ACQUIRE, __HIP_MEMORY_SCOPE_AGENT) < NPAIR)
            __builtin_amdgcn_s_sleep(2);
    }
    __syncthreads();
    __threadfence();                      // acquire: colcnt/colent now visible

    for (int j = tid; j < NN; j += NTH) {
        int cc = colcnt[base + j];
        u.s.ccL[j] = (unsigned char)((cc > CAP) ? CAP : cc);
    }
    __syncthreads();

    // ---- fixpoint: kept <=> no kept earlier overlapper ----
    while (true) {
        if (tid == 0) s_unres = 0;
        __syncthreads();
        int lu = 0;
        for (int j = tid; j < NN; j += NTH) {
            if (u.s.st[j] != 0) continue;
            int cc = u.s.ccL[j];
            const u16* lst = colent + (size_t)(base + j) * CAP;
            bool anyK = false, anyU = false;
            for (int e = 0; e < cc; ++e) {
                unsigned char s = u.s.st[lst[e]];
                anyK |= (s == 1);
                anyU |= (s == 0);
            }
            if (anyK) u.s.st[j] = 2;
            else if (!anyU) u.s.st[j] = 1;
            else ++lu;
        }
        lu = wredi(lu);
        if (lane == 0 && lu) atomicAdd(&s_unres, lu);
        __syncthreads();
        if (s_unres == 0) break;
        __syncthreads();                  // protect s_unres reset next round
    }

    // ---- pass 1: kept bookkeeping + killer attribution ----
    for (int j = tid; j < NN; j += NTH) {
        int g = gbi[j];
        if (u.s.st[j] == 1) {
            atomicMin(&s_minkey, u.s.keyL[j]);
            atomicMax(&u.s.firstk[g], u.s.keyL[j]);
        } else if (g >= 0) {
            int cc = u.s.ccL[j];
            const u16* lst = colent + (size_t)(base + j) * CAP;
            u64 bk = 0ull; int ki = -1;
            for (int e = 0; e < cc; ++e) {
                int ii = lst[e];
                if (u.s.st[ii] == 1 && u.s.keyL[ii] > bk) { bk = u.s.keyL[ii]; ki = ii; }
            }
            if (ki < 0) continue;         // cannot happen for a killed positive
            u.s.hk[ki] = 1;               // benign race: all write 1
            float v = iou4(load_box(pb, ki), load_box(pb, j));
            int gi = gbi[ki];
            if (g != gi && v > iou4(u.s.gtb[gi], u.s.gtb[g])) {
                atomicAdd(&u.s.cntA[ki], 1);
                atomicAdd(&u.s.sumA[ki], -logf(1.5f - v) * pb[j * 5 + 4]);
            }
        }
    }
    __syncthreads();

    // ---- pass 2: accumulation over kept selections (order-free) ----
    float ltpush = 0.f, ltpull = 0.f;
    int lqcnt = 0, lpcnt = 0;
    const u64 minkey = s_minkey;
    for (int i = tid; i < NN; i += NTH) {
        if (u.s.st[i] != 1) continue;
        int g = gbi[i];
        u64 fk = u.s.firstk[g];
        bool add = (u.s.keyL[i] != minkey) || (u.s.hk[i] != 0);  // any(alive_p)
        int c = u.s.cntA[i];
        bool hr = fk > u.s.keyL[i];                               // earlier kept, same gt
        if (add && c > 0) ltpush += u.s.sumA[i] / (float)c;
        if (add) lqcnt += c;
        if (hr) ++lpcnt;                                          // counted even when !add
        if (add && hr) {
            int r = (NN - 1) - (int)(fk & 0xffffffffu);
            float v = iou4(load_box(pb, i), load_box(pb, r));
            ltpull += -logf(fmaxf(v, 1e-6f)) * pb[i * 5 + 4];
        }
    }
    ltpush = wredf(ltpush); ltpull = wredf(ltpull);
    lqcnt = wredi(lqcnt); lpcnt = wredi(lpcnt);
    if (lane == 0) {
        if (ltpush != 0.f) atomicAdd(&s_tpush, ltpush);
        if (ltpull != 0.f) atomicAdd(&s_tpull, ltpull);
        if (lqcnt) atomicAdd(&s_qcnt, lqcnt);
        if (lpcnt) atomicAdd(&s_pcnt, lpcnt);
    }
    __syncthreads();

    // ---- cross-image finalize: last-finishing scan block writes the B-mean ----
    if (tid == 0) {
        float valid = (s_pos > 1) ? 1.0f : 0.0f;
        float push_b = s_tpush / ((float)s_qcnt + 1e-6f) * valid;
        float pull_b = s_tpull / ((float)s_pcnt + 1e-6f) * valid;
        atomicAdd(&acc[0], push_b);
        atomicAdd(&acc[1], pull_b);
        __threadfence();
        unsigned int old = atomicAdd(ctr2, 1u);
        if (old == (unsigned int)(B - 1)) {
            float ps = atomicAdd(&acc[0], 0.0f);   // coherent device-scope read
            float pl = atomicAdd(&acc[1], 0.0f);
            float inv = 1.0f / (float)B;
            out[0] = ps * inv * 1.0f;  // push_loss * PUSH_W
            out[1] = pl * inv * 1.0f;  // pull_loss * PULL_W
        }
    }
}

extern "C" void kernel_launch(void* const* d_in, const int* in_sizes, int n_in,
                              void* d_out, int out_size, void* d_ws, size_t ws_size,
                              hipStream_t stream) {
    // inputs: 0=gt_inds(B*N i32), 1=anchor_gt_inds(B*N i32),
    //         2=gt_bboxes(B*G*4 f32), 3=proposal_list(B*N*5 f32)
    const int B = in_sizes[0] / NN;
    const int* anchor_gt = (const int*)d_in[1];
    const float* gtb = (const float*)d_in[2];
    const float* props = (const float*)d_in[3];

    // ---- workspace layout: [zeroed header | colent] ----
    char* w = (char*)d_ws;
    int* colcnt = (int*)w;                     // B*NN*4
    int* ctrs = (int*)(w + (size_t)B * NN * 4);             // B ints
    float* acc = (float*)(w + (size_t)B * NN * 4 + B * 4);  // 2 floats
    unsigned int* ctr2 = (unsigned int*)(w + (size_t)B * NN * 4 + B * 4 + 8);
    size_t hdr = (size_t)B * NN * 4 + B * 4 + 8 + 4;
    hdr = (hdr + 15) & ~(size_t)15;
    u16* colent = (u16*)(w + hdr);             // B*NN*CAP*2

    hipMemsetAsync(d_ws, 0, hdr, stream);
    fused_kernel<<<dim3(B * NPAIR), dim3(NTH), 0, stream>>>(anchor_gt, gtb, props,
                                                            colcnt, colent, ctrs, acc, ctr2,
                                                            (float*)d_out, B);
}